// Round 1
// 684.422 us; speedup vs baseline: 1.4856x; 1.4856x over previous
//
#include <hip/hip_runtime.h>

#define B_ 2
#define H_ 16
#define S_ 2048
#define D_ 64

typedef short v8s __attribute__((ext_vector_type(8)));   // 8 bf16 (bit patterns) = 4 VGPRs
typedef float v4f __attribute__((ext_vector_type(4)));
typedef unsigned short u16;
typedef unsigned int   u32;
typedef unsigned long long u64;

// pack two fp32 -> two bf16 (round-half-up: +0x8000 then take high 16 via v_perm)
__device__ __forceinline__ u32 pk2(float a, float b) {
    u32 ua = __float_as_uint(a) + 0x8000u;
    u32 ub = __float_as_uint(b) + 0x8000u;
    return __builtin_amdgcn_perm(ub, ua, 0x07060302u);  // lo16=hi(ua), hi16=hi(ub)
}

// load 8 consecutive fp32, scale, convert to bf16x8 fragment
__device__ __forceinline__ v8s cvt8(const float* __restrict__ p, float s) {
    float4 x = ((const float4*)p)[0];
    float4 y = ((const float4*)p)[1];
    union { u32 u[4]; v8s v; } r;
    r.u[0] = pk2(x.x * s, x.y * s);
    r.u[1] = pk2(x.z * s, x.w * s);
    r.u[2] = pk2(y.x * s, y.y * s);
    r.u[3] = pk2(y.z * s, y.w * s);
    return r.v;
}

// async global->LDS, 16B per lane. dst is wave-uniform base + lane*16.
__device__ __forceinline__ void gll16(const void* g, void* l) {
    __builtin_amdgcn_global_load_lds(
        (const __attribute__((address_space(1))) u32*)g,
        (__attribute__((address_space(3))) u32*)l, 16, 0, 0);
}

// ---------------- prep kernels (fast path, workspace-backed) ----------------

// fp32 -> bf16, 8 elems/thread (K matrix)
__global__ void cvt_bf16_k(const float* __restrict__ src, u16* __restrict__ dst) {
    size_t i = (size_t)blockIdx.x * blockDim.x + threadIdx.x;
    const float* p = src + i * 8;
    float4 a = ((const float4*)p)[0], b = ((const float4*)p)[1];
    uint4 o;
    o.x = pk2(a.x, a.y); o.y = pk2(a.z, a.w);
    o.z = pk2(b.x, b.y); o.w = pk2(b.z, b.w);
    ((uint4*)dst)[i] = o;
}

// V[b,h,s,d] fp32 -> Vt[b,h,d,s'] bf16, where s' is kappa-interleaved within each
// 32-key group: u16 pair (word w = g*4+j1) = (key base+4g+j1, key base+16+4g+j1).
// This makes the PV B-fragment a single contiguous 16B LDS read.
__global__ void vtrans_k(const float* __restrict__ V, u16* __restrict__ Vt) {
    __shared__ u16 t[64][66];                       // +2 pad: odd dword stride
    const int bh = blockIdx.y, s0 = blockIdx.x * 64;
    const int tid = threadIdx.x;
    {
        const int r = tid >> 2, c0 = (tid & 3) * 16;
        const float* p = V + ((size_t)bh * S_ + s0 + r) * D_ + c0;
        float4 f0 = ((const float4*)p)[0], f1 = ((const float4*)p)[1];
        float4 f2 = ((const float4*)p)[2], f3 = ((const float4*)p)[3];
        u32* tw = (u32*)&t[r][c0];
        tw[0] = pk2(f0.x, f0.y); tw[1] = pk2(f0.z, f0.w);
        tw[2] = pk2(f1.x, f1.y); tw[3] = pk2(f1.z, f1.w);
        tw[4] = pk2(f2.x, f2.y); tw[5] = pk2(f2.z, f2.w);
        tw[6] = pk2(f3.x, f3.y); tw[7] = pk2(f3.z, f3.w);
    }
    __syncthreads();
    {
        const int d = tid >> 2, t2 = tid & 3;
        const int G = t2 >> 1, hh = t2 & 1;        // 32-key group, half of it
        const int e0 = G * 32 + hh * 8;
        u32 o[8];
        #pragma unroll
        for (int u = 0; u < 8; ++u)
            o[u] = (u32)t[e0 + u][d] | ((u32)t[e0 + 16 + u][d] << 16);
        u16* q = Vt + ((size_t)bh * D_ + d) * S_ + s0 + G * 32 + hh * 16;
        ((uint4*)q)[0] = make_uint4(o[0], o[1], o[2], o[3]);
        ((uint4*)q)[1] = make_uint4(o[4], o[5], o[6], o[7]);
    }
}

// mask int32 -> bitmask (1 bit/elem), linear order == flat index; ballot packs a wave
__global__ void mbits_k(const int* __restrict__ mask, u64* __restrict__ mb) {
    size_t i = (size_t)blockIdx.x * blockDim.x + threadIdx.x;
    u64 bal = __ballot(mask[i] != 0);
    if ((threadIdx.x & 63) == 0) mb[i >> 6] = bal;
}

// ---------------- main attention kernel (fast path) ----------------
// Block: 256 thr = 4 waves; wave w owns q-rows [qb*64 + w*16, +16).
// Pass A: rowsums of masked exp, K staged in LDS (128-key tiles, double-buffered,
//         global_load_lds, XOR-swizzled via pre-swizzled global source).
// Pass B: recompute QK, write P, O += P*V; K+V staged (64-key tiles, dbuf).
// 2-phase pipeline: STAGE(t+1); compute(t); __syncthreads() [implicit vmcnt(0)].
__global__ __launch_bounds__(256, 4)
void attn_fast(const float* __restrict__ Q, const u16* __restrict__ Kb,
               const u16* __restrict__ Vt, const u32* __restrict__ mbits,
               float* __restrict__ out, float* __restrict__ P)
{
    __shared__ __align__(16) char LS[32768];        // 2 x 16KB stage buffers
    __shared__ __align__(16) u16 pbuf[4][640];      // per-wave P->A-frag scratch (stride 80B)

    const int tid = threadIdx.x;
    const int w = tid >> 6, lane = tid & 63;
    const int n = lane & 15, g = lane >> 4;

    // XCD-aware swizzle: XCD x (= blockIdx.x % 8) owns hb in [4x, 4x+4) -> K/V L2-resident
    const int x = blockIdx.x;
    const int xcd = x & 7, kk = x >> 3;
    const int bh = xcd * 4 + (kk >> 5);             // 0..31
    const int qb = kk & 31;
    const int b = bh >> 4;
    const int q0 = qb * 64 + w * 16;

    // Q A-fragments, pre-scaled by 1/sqrt(64)=0.125 (exact in bf16)
    const float* qrow = Q + ((size_t)bh * S_ + q0 + n) * D_;
    const v8s aq0 = cvt8(qrow + g * 8, 0.125f);
    const v8s aq1 = cvt8(qrow + 32 + g * 8, 0.125f);

    // ---- staging constants ----
    // pass B: wave w stages K chunks {2w,2w+1}, V chunks {2w,2w+1} of its tile.
    // unit u = chunk*64+lane -> LDS row = u>>3, 16B-block bidx = u&7.
    // swizzle: LDS (row, x) holds global (row, x ^ (row&7))  [16B granularity]
    const int srow = 16 * w + (lane >> 3);
    const int swz16 = (((lane & 7) ^ (srow & 7)) << 4);
    const char* kB  = (const char*)(Kb + (size_t)bh * S_ * D_) + (size_t)srow * 128 + swz16;
    const char* vB  = (const char*)(Vt + (size_t)bh * D_ * S_) + (size_t)srow * 4096 + swz16;
    // pass A (128-row tiles): wave w stages chunks {4w..4w+3}; base row = 32w + lane>>3
    const char* kBA = (const char*)(Kb + (size_t)bh * S_ * D_)
                      + (size_t)(32 * w + (lane >> 3)) * 128 + swz16;

    // read-side swizzled column offset: row = s*16 + n  (row&7 == n&7)
    const int C = n * 128 + (((g) ^ (n & 7)) << 4);

    // mask bit words: row-major, 64 u32 words per q-row
    const u32* mrow = mbits + ((size_t)b * S_ + q0 + g * 4) * 64;

    // ---- Pass A: row sums of masked exp (128-key tiles, 16 iterations) ----
    v4f sum = {0.f, 0.f, 0.f, 0.f};
    {
        #pragma unroll
        for (int c = 0; c < 4; ++c)
            gll16(kBA + c * 1024, LS + (size_t)w * 4096 + c * 1024);
        uint4 mnx[4];
        #pragma unroll
        for (int i = 0; i < 4; ++i) mnx[i] = *(const uint4*)(mrow + i * 64);
        __syncthreads();

        for (int T = 0; T < 16; ++T) {
            const char* KA = LS + (T & 1) * 16384;
            if (T < 15) {
                const char* src = kBA + (size_t)(T + 1) * 16384;
                char* dst = LS + ((T + 1) & 1) * 16384 + (size_t)w * 4096;
                #pragma unroll
                for (int c = 0; c < 4; ++c) gll16(src + c * 1024, dst + c * 1024);
            }
            uint4 mc[4];
            #pragma unroll
            for (int i = 0; i < 4; ++i) mc[i] = mnx[i];
            if (T < 15) {
                #pragma unroll
                for (int i = 0; i < 4; ++i)
                    mnx[i] = *(const uint4*)(mrow + i * 64 + (T + 1) * 4);
            }
            v4f acc[8];
            __builtin_amdgcn_s_setprio(1);
            #pragma unroll
            for (int s = 0; s < 8; ++s) {
                v8s kf0 = *(const v8s*)(KA + s * 2048 + C);
                v8s kf1 = *(const v8s*)(KA + s * 2048 + (C ^ 64));
                v4f z = {0.f, 0.f, 0.f, 0.f};
                z = __builtin_amdgcn_mfma_f32_16x16x32_bf16(aq0, kf0, z, 0, 0, 0);
                acc[s] = __builtin_amdgcn_mfma_f32_16x16x32_bf16(aq1, kf1, z, 0, 0, 0);
            }
            __builtin_amdgcn_s_setprio(0);
            #pragma unroll
            for (int s = 0; s < 8; ++s) {
                #pragma unroll
                for (int i = 0; i < 4; ++i) {
                    u32 wrd = (s >> 1) == 0 ? mc[i].x : (s >> 1) == 1 ? mc[i].y
                            : (s >> 1) == 2 ? mc[i].z : mc[i].w;
                    float e = ((wrd >> ((s & 1) * 16 + n)) & 1) ? __expf(acc[s][i]) : 0.f;
                    sum[i] += e;
                }
            }
            __syncthreads();
        }
    }
    #pragma unroll
    for (int i = 0; i < 4; ++i) {
        float s2 = sum[i];
        s2 += __shfl_xor(s2, 1, 64);
        s2 += __shfl_xor(s2, 2, 64);
        s2 += __shfl_xor(s2, 4, 64);
        s2 += __shfl_xor(s2, 8, 64);
        sum[i] = 1.0f / s2;   // sum now holds inv
    }

    // ---- Pass B: write P, accumulate O = P*V (64-key K+V tiles, 32 iterations) ----
    float* pb = P + ((size_t)bh * S_ + q0 + g * 4) * S_ + n;
    char* ldsw = (char*)&pbuf[w][0];
    v4f o0 = {0.f, 0.f, 0.f, 0.f}, o1 = o0, o2 = o0, o3 = o0;
    {
        #pragma unroll
        for (int c = 0; c < 2; ++c) {
            gll16(kB + (size_t)c * 1024,  LS + (size_t)w * 2048 + c * 1024);
            gll16(vB + (size_t)c * 32768, LS + 8192 + (size_t)w * 2048 + c * 1024);
        }
        uint2 mnx[4];
        #pragma unroll
        for (int i = 0; i < 4; ++i) mnx[i] = *(const uint2*)(mrow + i * 64);
        __syncthreads();

        for (int t = 0; t < 32; ++t) {
            const char* Kc = LS + (t & 1) * 16384;
            const char* Vc = Kc + 8192;
            if (t < 31) {
                char* dstb = LS + ((t + 1) & 1) * 16384;
                const char* ks = kB + (size_t)(t + 1) * 8192;
                const char* vs = vB + (size_t)(t + 1) * 128;
                #pragma unroll
                for (int c = 0; c < 2; ++c) {
                    gll16(ks + (size_t)c * 1024,  dstb + (size_t)w * 2048 + c * 1024);
                    gll16(vs + (size_t)c * 32768, dstb + 8192 + (size_t)w * 2048 + c * 1024);
                }
            }
            uint2 mc[4];
            #pragma unroll
            for (int i = 0; i < 4; ++i) mc[i] = mnx[i];
            if (t < 31) {
                #pragma unroll
                for (int i = 0; i < 4; ++i)
                    mnx[i] = *(const uint2*)(mrow + i * 64 + (t + 1) * 2);
            }
            v4f a[4];
            __builtin_amdgcn_s_setprio(1);
            #pragma unroll
            for (int s = 0; s < 4; ++s) {
                v8s kf0 = *(const v8s*)(Kc + s * 2048 + C);
                v8s kf1 = *(const v8s*)(Kc + s * 2048 + (C ^ 64));
                v4f z = {0.f, 0.f, 0.f, 0.f};
                z = __builtin_amdgcn_mfma_f32_16x16x32_bf16(aq0, kf0, z, 0, 0, 0);
                a[s] = __builtin_amdgcn_mfma_f32_16x16x32_bf16(aq1, kf1, z, 0, 0, 0);
            }
            __builtin_amdgcn_s_setprio(0);
            float* pt = pb + (size_t)t * 64;
            #pragma unroll
            for (int kg = 0; kg < 2; ++kg) {
                #pragma unroll
                for (int i = 0; i < 4; ++i) {
                    u32 wrd = kg ? mc[i].y : mc[i].x;
                    float p0 = ((wrd >> n) & 1)        ? __expf(a[2 * kg][i])     * sum[i] : 0.f;
                    float p1 = ((wrd >> (n + 16)) & 1) ? __expf(a[2 * kg + 1][i]) * sum[i] : 0.f;
                    pt[(size_t)i * S_ + kg * 32]      = p0;
                    pt[(size_t)i * S_ + kg * 32 + 16] = p1;
                    *(u32*)(ldsw + (g * 4 + i) * 80 + n * 4) = pk2(p0, p1);
                }
                v8s ap = *(const v8s*)(ldsw + n * 80 + g * 16);
                __builtin_amdgcn_s_setprio(1);
                v8s vf0 = *(const v8s*)(Vc + 0 * 2048 + (C ^ (kg << 6)));
                v8s vf1 = *(const v8s*)(Vc + 1 * 2048 + (C ^ (kg << 6)));
                v8s vf2 = *(const v8s*)(Vc + 2 * 2048 + (C ^ (kg << 6)));
                v8s vf3 = *(const v8s*)(Vc + 3 * 2048 + (C ^ (kg << 6)));
                o0 = __builtin_amdgcn_mfma_f32_16x16x32_bf16(ap, vf0, o0, 0, 0, 0);
                o1 = __builtin_amdgcn_mfma_f32_16x16x32_bf16(ap, vf1, o1, 0, 0, 0);
                o2 = __builtin_amdgcn_mfma_f32_16x16x32_bf16(ap, vf2, o2, 0, 0, 0);
                o3 = __builtin_amdgcn_mfma_f32_16x16x32_bf16(ap, vf3, o3, 0, 0, 0);
                __builtin_amdgcn_s_setprio(0);
            }
            __syncthreads();
        }
    }

    float* obase = out + ((size_t)bh * S_ + q0 + g * 4) * D_ + n;
    #pragma unroll
    for (int i = 0; i < 4; ++i) {
        obase[(size_t)i * D_]      = o0[i];
        obase[(size_t)i * D_ + 16] = o1[i];
        obase[(size_t)i * D_ + 32] = o2[i];
        obase[(size_t)i * D_ + 48] = o3[i];
    }
}

// ---------------- fallback (no workspace): original direct-fp32 path ----------------
__global__ __launch_bounds__(256, 4)
void attn_fb(const float* __restrict__ Q, const float* __restrict__ K,
             const float* __restrict__ V, const int* __restrict__ mask,
             float* __restrict__ out, float* __restrict__ P)
{
    __shared__ u16 ldsbuf[4][640];
    const int tid = threadIdx.x;
    const int w = tid >> 6, lane = tid & 63;
    const int n = lane & 15, g = lane >> 4;
    const int qb = blockIdx.x, h = blockIdx.y, b = blockIdx.z;
    const int bh = b * H_ + h;
    const int q0 = qb * 64 + w * 16;

    const float* qrow = Q + ((size_t)bh * S_ + q0 + n) * D_;
    const v8s aq0 = cvt8(qrow + g * 8, 0.125f);
    const v8s aq1 = cvt8(qrow + 32 + g * 8, 0.125f);

    const int* mrow = mask + ((size_t)b * S_ + q0 + g * 4) * S_ + n;
    const float* kfbase = K + ((size_t)bh * S_ + n) * D_ + g * 8;

    auto loadK = [&](int key0, int dh) -> v8s {
        return cvt8(kfbase + (size_t)key0 * D_ + dh * 32, 1.0f);
    };
    auto loadM = [&](int i, int k0) -> u32 {
        u32 r = 0;
        if (mrow[(size_t)i * S_ + k0]) r |= 1u << n;
        if (mrow[(size_t)i * S_ + k0 + 16]) r |= 1u << (n + 16);
        return r;
    };
    auto loadV = [&](int k0, int dt) -> v8s {
        union { u32 u[4]; v8s v; } r;
        const float* vp = V + ((size_t)bh * S_ + k0 + g * 4) * D_ + dt * 16 + n;
        #pragma unroll
        for (int p2 = 0; p2 < 4; ++p2) {
            float fa = vp[(size_t)p2 * D_];
            float fb = vp[(size_t)(16 + p2) * D_];
            r.u[p2] = pk2(fa, fb);
        }
        return r.v;
    };

    v4f sum = {0.f, 0.f, 0.f, 0.f};
    for (int k0 = 0; k0 < S_; k0 += 32) {
        v4f a0 = {0.f, 0.f, 0.f, 0.f}, a1 = {0.f, 0.f, 0.f, 0.f};
        a0 = __builtin_amdgcn_mfma_f32_16x16x32_bf16(aq0, loadK(k0, 0), a0, 0, 0, 0);
        a0 = __builtin_amdgcn_mfma_f32_16x16x32_bf16(aq1, loadK(k0, 1), a0, 0, 0, 0);
        a1 = __builtin_amdgcn_mfma_f32_16x16x32_bf16(aq0, loadK(k0 + 16, 0), a1, 0, 0, 0);
        a1 = __builtin_amdgcn_mfma_f32_16x16x32_bf16(aq1, loadK(k0 + 16, 1), a1, 0, 0, 0);
        #pragma unroll
        for (int i = 0; i < 4; ++i) {
            u32 mw = loadM(i, k0);
            float e0 = ((mw >> n) & 1) ? __expf(a0[i]) : 0.f;
            float e1 = ((mw >> (n + 16)) & 1) ? __expf(a1[i]) : 0.f;
            sum[i] += e0 + e1;
        }
    }
    #pragma unroll
    for (int i = 0; i < 4; ++i) {
        float s = sum[i];
        s += __shfl_xor(s, 1, 64);
        s += __shfl_xor(s, 2, 64);
        s += __shfl_xor(s, 4, 64);
        s += __shfl_xor(s, 8, 64);
        sum[i] = 1.0f / s;
    }

    char* ldsw = (char*)&ldsbuf[w][0];
    float* pbase = P + ((size_t)bh * S_ + q0 + g * 4) * S_ + n;
    v4f o0 = {0.f, 0.f, 0.f, 0.f}, o1 = o0, o2 = o0, o3 = o0;

    for (int k0 = 0; k0 < S_; k0 += 32) {
        v4f a0 = {0.f, 0.f, 0.f, 0.f}, a1 = {0.f, 0.f, 0.f, 0.f};
        a0 = __builtin_amdgcn_mfma_f32_16x16x32_bf16(aq0, loadK(k0, 0), a0, 0, 0, 0);
        a0 = __builtin_amdgcn_mfma_f32_16x16x32_bf16(aq1, loadK(k0, 1), a0, 0, 0, 0);
        a1 = __builtin_amdgcn_mfma_f32_16x16x32_bf16(aq0, loadK(k0 + 16, 0), a1, 0, 0, 0);
        a1 = __builtin_amdgcn_mfma_f32_16x16x32_bf16(aq1, loadK(k0 + 16, 1), a1, 0, 0, 0);
        #pragma unroll
        for (int i = 0; i < 4; ++i) {
            u32 mw = loadM(i, k0);
            float p0 = ((mw >> n) & 1) ? __expf(a0[i]) * sum[i] : 0.f;
            float p1 = ((mw >> (n + 16)) & 1) ? __expf(a1[i]) * sum[i] : 0.f;
            pbase[(size_t)i * S_ + k0] = p0;
            pbase[(size_t)i * S_ + k0 + 16] = p1;
            *(u32*)(ldsw + (g * 4 + i) * 80 + (n >> 2) * 16 + (n & 3) * 4) = pk2(p0, p1);
        }
        v8s ap = *(const v8s*)(ldsw + n * 80 + g * 16);
        o0 = __builtin_amdgcn_mfma_f32_16x16x32_bf16(ap, loadV(k0, 0), o0, 0, 0, 0);
        o1 = __builtin_amdgcn_mfma_f32_16x16x32_bf16(ap, loadV(k0, 1), o1, 0, 0, 0);
        o2 = __builtin_amdgcn_mfma_f32_16x16x32_bf16(ap, loadV(k0, 2), o2, 0, 0, 0);
        o3 = __builtin_amdgcn_mfma_f32_16x16x32_bf16(ap, loadV(k0, 3), o3, 0, 0, 0);
    }

    float* obase = out + ((size_t)bh * S_ + q0 + g * 4) * D_ + n;
    #pragma unroll
    for (int i = 0; i < 4; ++i) {
        obase[(size_t)i * D_]      = o0[i];
        obase[(size_t)i * D_ + 16] = o1[i];
        obase[(size_t)i * D_ + 32] = o2[i];
        obase[(size_t)i * D_ + 48] = o3[i];
    }
}

extern "C" void kernel_launch(void* const* d_in, const int* in_sizes, int n_in,
                              void* d_out, int out_size, void* d_ws, size_t ws_size,
                              hipStream_t stream)
{
    (void)in_sizes; (void)n_in; (void)out_size;
    const float* Q = (const float*)d_in[0];
    const float* K = (const float*)d_in[1];
    const float* V = (const float*)d_in[2];
    const int* mask = (const int*)d_in[3];
    float* out = (float*)d_out;
    float* P = out + (size_t)B_ * H_ * S_ * D_;   // p_attn follows out in d_out

    const size_t kb_b = (size_t)B_ * H_ * S_ * D_ * 2;  // 8 MB  bf16 K
    const size_t vt_b = kb_b;                            // 8 MB  bf16 V^T (kappa)
    const size_t mb_b = (size_t)B_ * S_ * S_ / 8;        // 1 MB  mask bits

    if (ws_size >= kb_b + vt_b + mb_b) {
        u16* Kb = (u16*)d_ws;
        u16* Vt = (u16*)((char*)d_ws + kb_b);
        u64* mb = (u64*)((char*)d_ws + kb_b + vt_b);
        cvt_bf16_k<<<(B_ * H_ * S_ * D_) / (256 * 8), 256, 0, stream>>>(K, Kb);
        vtrans_k<<<dim3(S_ / 64, B_ * H_), 256, 0, stream>>>(V, Vt);
        mbits_k<<<(B_ * S_ * S_) / 256, 256, 0, stream>>>(mask, mb);
        attn_fast<<<B_ * H_ * (S_ / 64), 256, 0, stream>>>(Q, Kb, Vt, (const u32*)mb, out, P);
    } else {
        attn_fb<<<dim3(S_ / 64, H_, B_), 256, 0, stream>>>(Q, K, V, mask, out, P);
    }
}